// Round 4
// baseline (1922.930 us; speedup 1.0000x reference)
//
#include <hip/hip_runtime.h>
#include <hip/hip_bf16.h>
#include <hip/hip_cooperative_groups.h>

namespace cg = cooperative_groups;

#define F_IN 512
#define NC 64      // HID == N_CLS == 64
#define NITER 10
#define BM 64      // MLP tile rows
#define BK 64      // MLP K tile
#define G_COOP 1024
#define NPB 49     // nodes per block in coop kernel: 1024*49 = 50176 >= 50000

// ---------------------------------------------------------------------------
// Init per-node halting state (fallback path); also set rowptr[N] = E.
__global__ __launch_bounds__(256) void init_state_kernel(
    float* __restrict__ steps, float* __restrict__ sumh, int* __restrict__ cont,
    int* __restrict__ rowptr, int N, int E) {
  int i = blockIdx.x * blockDim.x + threadIdx.x;
  if (i < N) { steps[i] = 1.0f; sumh[i] = 0.0f; cont[i] = 1; }
  if (i == 0) rowptr[N] = E;
}

// ---------------------------------------------------------------------------
// Fused tiled MLP: out[r,:] = relu(x[r,:] @ W1 + b1) @ W2 + b2   (all fp32)
// Block: 64 rows x 64 cols, 256 threads, 4x4 outputs per thread.
// xT layout: element (k, r) at xT[k*64 + (r ^ (k & 28))]  (2-way max on LDS).
__global__ __launch_bounds__(256) void mlp_kernel(
    const float* __restrict__ x, const float* __restrict__ W1,
    const float* __restrict__ b1, const float* __restrict__ W2,
    const float* __restrict__ b2, float* __restrict__ out, int N) {
  __shared__ float xT[BK * BM];    // swizzled [k][row] x tile / later hT
  __shared__ float ws[BK * NC];    // W1 k-tile / later W2
  const int tid  = threadIdx.x;
  const int brow = blockIdx.x * BM;
  const int r0 = (tid >> 4) * 4;   // 16 row-groups of 4
  const int c0 = (tid & 15) * 4;   // 16 col-groups of 4

  float acc[4][4];
#pragma unroll
  for (int j = 0; j < 4; ++j) {
    float bv = b1[c0 + j];
#pragma unroll
    for (int i = 0; i < 4; ++i) acc[i][j] = bv;
  }

  for (int kt = 0; kt < F_IN; kt += BK) {
    // stage x tile (64 rows x 64 k), transposed+swizzled into xT
#pragma unroll
    for (int q = 0; q < 4; ++q) {
      int fidx = q * 256 + tid;          // over 1024 float4s
      int row = fidx >> 4, kq = fidx & 15;
      int gr = brow + row; if (gr >= N) gr = N - 1;
      float4 v = *reinterpret_cast<const float4*>(&x[(size_t)gr * F_IN + kt + kq * 4]);
      float vv[4] = {v.x, v.y, v.z, v.w};
#pragma unroll
      for (int j = 0; j < 4; ++j) {
        int kk = kq * 4 + j;
        xT[kk * BM + (row ^ (kk & 28))] = vv[j];
      }
    }
    // stage W1 k-tile (64 x 64), row-major
#pragma unroll
    for (int q = 0; q < 4; ++q) {
      int fidx = q * 256 + tid;          // over 1024 float4s
      int row = fidx >> 4, kq = fidx & 15;
      *reinterpret_cast<float4*>(&ws[row * NC + kq * 4]) =
          *reinterpret_cast<const float4*>(&W1[(size_t)(kt + row) * NC + kq * 4]);
    }
    __syncthreads();
#pragma unroll 8
    for (int k = 0; k < BK; ++k) {
      float4 xa = *reinterpret_cast<const float4*>(&xT[k * BM + (r0 ^ (k & 28))]);
      float4 wv = *reinterpret_cast<const float4*>(&ws[k * NC + c0]);
      float xr[4] = {xa.x, xa.y, xa.z, xa.w};
      float wr[4] = {wv.x, wv.y, wv.z, wv.w};
#pragma unroll
      for (int i = 0; i < 4; ++i)
#pragma unroll
        for (int j = 0; j < 4; ++j) acc[i][j] = fmaf(xr[i], wr[j], acc[i][j]);
    }
    __syncthreads();
  }

  // ReLU; write h transposed+swizzled into xT space; stage W2 into ws
#pragma unroll
  for (int i = 0; i < 4; ++i)
#pragma unroll
    for (int j = 0; j < 4; ++j) {
      int kk = c0 + j;
      int r  = r0 + i;
      xT[kk * BM + (r ^ (kk & 28))] = fmaxf(acc[i][j], 0.0f);
    }
#pragma unroll
  for (int q = 0; q < 4; ++q) {
    int fidx = q * 256 + tid;
    int row = fidx >> 4, kq = fidx & 15;
    *reinterpret_cast<float4*>(&ws[row * NC + kq * 4]) =
        *reinterpret_cast<const float4*>(&W2[(size_t)row * NC + kq * 4]);
  }
  float acc2[4][4];
#pragma unroll
  for (int j = 0; j < 4; ++j) {
    float bv = b2[c0 + j];
#pragma unroll
    for (int i = 0; i < 4; ++i) acc2[i][j] = bv;
  }
  __syncthreads();
#pragma unroll 8
  for (int k = 0; k < NC; ++k) {
    float4 xa = *reinterpret_cast<const float4*>(&xT[k * BM + (r0 ^ (k & 28))]);
    float4 wv = *reinterpret_cast<const float4*>(&ws[k * NC + c0]);
    float xr[4] = {xa.x, xa.y, xa.z, xa.w};
    float wr[4] = {wv.x, wv.y, wv.z, wv.w};
#pragma unroll
    for (int i = 0; i < 4; ++i)
#pragma unroll
      for (int j = 0; j < 4; ++j) acc2[i][j] = fmaf(xr[i], wr[j], acc2[i][j]);
  }
#pragma unroll
  for (int i = 0; i < 4; ++i) {
    int gr = brow + r0 + i;
    if (gr < N) {
      float4 o = make_float4(acc2[i][0], acc2[i][1], acc2[i][2], acc2[i][3]);
      *reinterpret_cast<float4*>(&out[(size_t)gr * NC + c0]) = o;
    }
  }
}

// ---------------------------------------------------------------------------
// Degree histograms: deg_i counts sources (for GCN norm), indeg counts
// destinations (for the pull-CSR). Int atomics -> deterministic.
__global__ __launch_bounds__(256) void hist_kernel(
    const int* __restrict__ ei, int* __restrict__ deg_i,
    int* __restrict__ indeg, int E) {
  int e = blockIdx.x * blockDim.x + threadIdx.x;
  if (e < E) {
    atomicAdd(&deg_i[ei[e]], 1);       // row = edge_index[0]
    atomicAdd(&indeg[ei[E + e]], 1);   // col = edge_index[1]
  }
}

// dis[i] = 1/sqrt(deg_i[i] + 1)   (+1 = self loop; deg always >= 1)
__global__ __launch_bounds__(256) void dis_kernel(
    const int* __restrict__ deg_i, float* __restrict__ dis, int N) {
  int i = blockIdx.x * blockDim.x + threadIdx.x;
  if (i < N) dis[i] = 1.0f / sqrtf((float)(deg_i[i] + 1));
}

// ---------------------------------------------------------------------------
// 3-kernel exclusive scan of indeg -> rowptr  (N = 50000, 196 blocks of 256)
__global__ __launch_bounds__(256) void scan_sum_kernel(
    const int* __restrict__ indeg, int* __restrict__ bsum, int N) {
  __shared__ int sm[256];
  int tid = threadIdx.x;
  int i = blockIdx.x * 256 + tid;
  sm[tid] = (i < N) ? indeg[i] : 0;
  __syncthreads();
  for (int s = 128; s > 0; s >>= 1) {
    if (tid < s) sm[tid] += sm[tid + s];
    __syncthreads();
  }
  if (tid == 0) bsum[blockIdx.x] = sm[0];
}

__global__ __launch_bounds__(256) void scan_bsum_kernel(int* __restrict__ bsum, int nb) {
  __shared__ int sm[256];
  int tid = threadIdx.x;
  int v = (tid < nb) ? bsum[tid] : 0;
  sm[tid] = v;
  __syncthreads();
  for (int s = 1; s < 256; s <<= 1) {
    int t = (tid >= s) ? sm[tid - s] : 0;
    __syncthreads();
    sm[tid] += t;
    __syncthreads();
  }
  if (tid < nb) bsum[tid] = sm[tid] - v;  // exclusive
}

__global__ __launch_bounds__(256) void scan_final_kernel(
    const int* __restrict__ indeg, const int* __restrict__ bsum,
    int* __restrict__ rowptr, int N) {
  __shared__ int sm[256];
  int tid = threadIdx.x;
  int i = blockIdx.x * 256 + tid;
  int v = (i < N) ? indeg[i] : 0;
  sm[tid] = v;
  __syncthreads();
  for (int s = 1; s < 256; s <<= 1) {
    int t = (tid >= s) ? sm[tid - s] : 0;
    __syncthreads();
    sm[tid] += t;
    __syncthreads();
  }
  if (i < N) rowptr[i] = bsum[blockIdx.x] + sm[tid] - v;
}

// ---------------------------------------------------------------------------
// Build destination-CSR entries: csr[pos] = {src, norm} packed as int2.
__global__ __launch_bounds__(256) void scatter_kernel(
    const int* __restrict__ ei, const int* __restrict__ rowptr,
    int* __restrict__ cursor, const float* __restrict__ dis,
    int2* __restrict__ csr, int E) {
  int e = blockIdx.x * blockDim.x + threadIdx.x;
  if (e < E) {
    int s = ei[e];
    int c = ei[E + e];
    int pos = rowptr[c] + atomicAdd(&cursor[c], 1);
    csr[pos] = make_int2(s, __float_as_int(dis[s] * dis[c]));
  }
}

// ---------------------------------------------------------------------------
// Cooperative kernel: all 10 adaptive-propagation steps + final log_softmax.
// 1024 blocks x 256 threads, 4 blocks/CU co-resident (LDS 26.3KB, VGPR<=128).
// Each block owns NPB=49 nodes; per-node state lives in LDS across iters.
__global__ __launch_bounds__(256, 4) void prop_all_kernel(
    float* __restrict__ bufA, float* __restrict__ bufB,
    const int2* __restrict__ csr, const int* __restrict__ rowptr,
    const float* __restrict__ dis, const float* __restrict__ hw,
    const float* __restrict__ hb,
    float* __restrict__ out0, float* __restrict__ out1,
    float* __restrict__ out2, int N) {
  cg::grid_group grid = cg::this_grid();
  __shared__ float accrow[NPB][NC];   // this block's current prop rows
  __shared__ float xach[NPB][NC];     // xacc accumulator
  __shared__ float stA[NPB], shA[NPB], dcA[NPB];
  __shared__ int ctA[NPB], begA[NPB], endA[NPB];

  const int wv = threadIdx.x >> 6;    // wave 0..3; wave w owns j = w, w+4, ...
  const int lane = threadIdx.x & 63;
  const int base = blockIdx.x * NPB;
  const float hwl = hw[lane];
  const float hb0 = hb[0];

  for (int j = wv; j < NPB; j += 4) {
    int node = base + j;
    if (node < N) {
      accrow[j][lane] = bufA[(size_t)node * NC + lane];
      xach[j][lane] = 0.0f;
      if (lane == 0) {
        stA[j] = 1.0f; shA[j] = 0.0f; ctA[j] = 1;
        dcA[j] = dis[node];
        begA[j] = rowptr[node];
        endA[j] = rowptr[node + 1];
      }
    }
  }
  __syncthreads();

  const float* cur = bufA;
  float* nxt = bufB;
  for (int it = 0; it < NITER; ++it) {
    if (it) grid.sync();   // prev iter's prop writes visible device-wide
    for (int j = wv; j < NPB; j += 4) {
      int node = base + j;
      if (node >= N) continue;
      float oldv = accrow[j][lane];
      float dc = dcA[j];
      int beg = begA[j], iend = endA[j];
      float a[8];
      a[0] = dc * dc * oldv;            // self-loop: norm = dis[c]^2
#pragma unroll
      for (int u = 1; u < 8; ++u) a[u] = 0.0f;
      int i = beg;
      for (; i + 8 <= iend; i += 8) {   // 8 outstanding gathers
        int2 e[8];
#pragma unroll
        for (int u = 0; u < 8; ++u) e[u] = csr[i + u];
#pragma unroll
        for (int u = 0; u < 8; ++u)
          a[u] = fmaf(__int_as_float(e[u].y), cur[(size_t)e[u].x * NC + lane], a[u]);
      }
      for (; i < iend; ++i) {
        int2 e0 = csr[i];
        a[0] = fmaf(__int_as_float(e0.y), cur[(size_t)e0.x * NC + lane], a[0]);
      }
      float acc = ((a[0] + a[1]) + (a[2] + a[3])) + ((a[4] + a[5]) + (a[6] + a[7]));
      nxt[(size_t)node * NC + lane] = acc;
      accrow[j][lane] = acc;

      // hh = sigmoid(acc . halt_w + halt_b)
      float z = acc * hwl;
#pragma unroll
      for (int off = 32; off > 0; off >>= 1) z += __shfl_xor(z, off);
      z += hb0;
      float hh = 1.0f / (1.0f + expf(-z));

      float st = stA[j], sh = shA[j];
      int ct = ctA[j];
      bool prob = ((sh + hh) < 0.99f) && (ct != 0);
      float pf = prob ? 1.0f : 0.0f;
      st += pf;
      sh += pf * hh;
      bool cond = prob && (st < (float)NITER);
      float pp = cond ? sh : (1.0f - sh);
      float ctf = ct ? 1.0f : 0.0f;
      xach[j][lane] += (acc * pp + oldv * (1.0f - pp)) * ctf;
      if (lane == 0) { stA[j] = st; shA[j] = sh; ctA[j] = prob ? 1 : 0; }
    }
    { const float* t = nxt; nxt = (float*)cur; cur = t; }
  }
  __syncthreads();   // make lane0's last stA/shA writes visible to all lanes

  // fused final: out0 = log_softmax(xacc/steps), out1 = steps, out2 = 1-sum_h
  for (int j = wv; j < NPB; j += 4) {
    int node = base + j;
    if (node >= N) continue;
    float st = stA[j];
    float v = xach[j][lane] / st;
    float m = v;
#pragma unroll
    for (int off = 32; off > 0; off >>= 1) m = fmaxf(m, __shfl_xor(m, off));
    float e = expf(v - m);
    float s = e;
#pragma unroll
    for (int off = 32; off > 0; off >>= 1) s += __shfl_xor(s, off);
    out0[(size_t)node * NC + lane] = v - m - logf(s);
    if (lane == 0) { out1[node] = st; out2[node] = 1.0f - shA[j]; }
  }
}

// ---------------------------------------------------------------------------
// Fallback single prop step (used only if cooperative launch is unavailable).
__global__ __launch_bounds__(256) void prop_step_kernel(
    const float* __restrict__ prop, float* __restrict__ prop_new,
    const int2* __restrict__ csr, const int* __restrict__ rowptr,
    const float* __restrict__ dis, const float* __restrict__ hw,
    const float* __restrict__ hb, float* __restrict__ steps,
    float* __restrict__ sumh, int* __restrict__ cont,
    float* __restrict__ xacc, int N) {
  int wid = (int)((blockIdx.x * blockDim.x + threadIdx.x) >> 6);
  if (wid >= N) return;
  int lane = threadIdx.x & 63;
  size_t rowoff = (size_t)wid * NC + lane;

  float oldv = prop[rowoff];
  float dc = dis[wid];
  int beg = __builtin_amdgcn_readfirstlane(rowptr[wid]);
  int end = __builtin_amdgcn_readfirstlane(rowptr[wid + 1]);

  float a[8];
  a[0] = dc * dc * oldv;
#pragma unroll
  for (int u = 1; u < 8; ++u) a[u] = 0.0f;
  int i = beg;
  for (; i + 8 <= end; i += 8) {
    int2 e[8];
#pragma unroll
    for (int u = 0; u < 8; ++u) e[u] = csr[i + u];
#pragma unroll
    for (int u = 0; u < 8; ++u)
      a[u] = fmaf(__int_as_float(e[u].y), prop[(size_t)e[u].x * NC + lane], a[u]);
  }
  for (; i < end; ++i) {
    int2 e0 = csr[i];
    a[0] = fmaf(__int_as_float(e0.y), prop[(size_t)e0.x * NC + lane], a[0]);
  }
  float acc = ((a[0] + a[1]) + (a[2] + a[3])) + ((a[4] + a[5]) + (a[6] + a[7]));
  prop_new[rowoff] = acc;

  float z = acc * hw[lane];
#pragma unroll
  for (int off = 32; off > 0; off >>= 1) z += __shfl_xor(z, off);
  z += hb[0];
  float hh = 1.0f / (1.0f + expf(-z));

  float st = steps[wid], sh = sumh[wid];
  int ct = cont[wid];
  bool prob = ((sh + hh) < 0.99f) && (ct != 0);
  float pf = prob ? 1.0f : 0.0f;
  st += pf;
  sh += pf * hh;
  bool cond = prob && (st < (float)NITER);
  float pp = cond ? sh : (1.0f - sh);
  float ctf = ct ? 1.0f : 0.0f;
  xacc[rowoff] += (acc * pp + oldv * (1.0f - pp)) * ctf;
  if (lane == 0) { steps[wid] = st; sumh[wid] = sh; cont[wid] = prob ? 1 : 0; }
}

// Fallback final kernel.
__global__ __launch_bounds__(256) void final_kernel(
    const float* __restrict__ xacc, const float* __restrict__ steps,
    const float* __restrict__ sumh, float* __restrict__ out0,
    float* __restrict__ out1, float* __restrict__ out2, int N) {
  int wid = (int)((blockIdx.x * blockDim.x + threadIdx.x) >> 6);
  if (wid >= N) return;
  int lane = threadIdx.x & 63;
  float st = steps[wid];
  float v = xacc[(size_t)wid * NC + lane] / st;
  float m = v;
#pragma unroll
  for (int off = 32; off > 0; off >>= 1) m = fmaxf(m, __shfl_xor(m, off));
  float e = expf(v - m);
  float s = e;
#pragma unroll
  for (int off = 32; off > 0; off >>= 1) s += __shfl_xor(s, off);
  out0[(size_t)wid * NC + lane] = v - m - logf(s);
  if (lane == 0) { out1[wid] = st; out2[wid] = 1.0f - sumh[wid]; }
}

// ---------------------------------------------------------------------------
extern "C" void kernel_launch(void* const* d_in, const int* in_sizes, int n_in,
                              void* d_out, int out_size, void* d_ws, size_t ws_size,
                              hipStream_t stream) {
  const float* x      = (const float*)d_in[0];
  const int*   ei     = (const int*)d_in[1];
  const float* W1     = (const float*)d_in[2];
  const float* b1     = (const float*)d_in[3];
  const float* W2     = (const float*)d_in[4];
  const float* b2     = (const float*)d_in[5];
  const float* halt_w = (const float*)d_in[6];
  const float* halt_b = (const float*)d_in[7];

  const int N = in_sizes[0] / F_IN;   // 50000
  const int E = in_sizes[1] / 2;      // 800000

  // workspace carve-up (256B aligned)
  char* p = (char*)d_ws;
  auto alloc = [&](size_t bytes) {
    void* r = (void*)p;
    p += (bytes + 255) & ~(size_t)255;
    return r;
  };
  float* propA  = (float*)alloc((size_t)N * NC * 4);
  float* propB  = (float*)alloc((size_t)N * NC * 4);
  float* xacc   = (float*)alloc((size_t)N * NC * 4);
  int2*  csr    = (int2*)alloc((size_t)E * 8);
  int*   rowptr = (int*)alloc((size_t)(N + 1) * 4);
  int*   deg_i  = (int*)alloc((size_t)N * 4);
  int*   indeg  = (int*)alloc((size_t)N * 4);
  int*   cursor = (int*)alloc((size_t)N * 4);
  float* dis    = (float*)alloc((size_t)N * 4);
  float* steps  = (float*)alloc((size_t)N * 4);
  float* sumh   = (float*)alloc((size_t)N * 4);
  int*   cont   = (int*)alloc((size_t)N * 4);
  int*   bsum   = (int*)alloc(1024);

  hipMemsetAsync(deg_i,  0, (size_t)N * 4, stream);
  hipMemsetAsync(indeg,  0, (size_t)N * 4, stream);
  hipMemsetAsync(cursor, 0, (size_t)N * 4, stream);
  hipMemsetAsync(xacc,   0, (size_t)N * NC * 4, stream);

  const int nbN = (N + 255) / 256;   // 196
  const int nbE = (E + 255) / 256;   // 3125
  const int nbM = (N + BM - 1) / BM; // 782

  init_state_kernel<<<nbN, 256, 0, stream>>>(steps, sumh, cont, rowptr, N, E);
  mlp_kernel<<<nbM, 256, 0, stream>>>(x, W1, b1, W2, b2, propA, N);
  hist_kernel<<<nbE, 256, 0, stream>>>(ei, deg_i, indeg, E);
  dis_kernel<<<nbN, 256, 0, stream>>>(deg_i, dis, N);
  scan_sum_kernel<<<nbN, 256, 0, stream>>>(indeg, bsum, N);
  scan_bsum_kernel<<<1, 256, 0, stream>>>(bsum, nbN);
  scan_final_kernel<<<nbN, 256, 0, stream>>>(indeg, bsum, rowptr, N);
  scatter_kernel<<<nbE, 256, 0, stream>>>(ei, rowptr, cursor, dis, csr, E);

  float* out0 = (float*)d_out;
  float* out1 = out0 + (size_t)N * NC;
  float* out2 = out1 + N;

  // Cooperative fused path (all 10 iters + final in one kernel).
  float* bA = propA;
  float* bB = propB;
  const int2* csrc = csr;
  const int* rpc = rowptr;
  const float* disc = dis;
  const float* hwc = halt_w;
  const float* hbc = halt_b;
  int Nc = N;
  void* kargs[11] = {&bA, &bB, &csrc, &rpc, &disc, &hwc, &hbc,
                     &out0, &out1, &out2, &Nc};
  hipError_t ce = hipLaunchCooperativeKernel(
      (const void*)prop_all_kernel, dim3(G_COOP), dim3(256), kargs, 0, stream);

  if (ce != hipSuccess) {
    // Fallback: 10 separate prop launches + final (known-good path).
    const float* cur = propA;
    float* nxt = propB;
    const int nbW = (N + 3) / 4;
    for (int it = 0; it < NITER; ++it) {
      prop_step_kernel<<<nbW, 256, 0, stream>>>(cur, nxt, csr, rowptr, dis,
                                                halt_w, halt_b, steps, sumh,
                                                cont, xacc, N);
      const float* t = nxt; nxt = (float*)cur; cur = t;
    }
    final_kernel<<<nbW, 256, 0, stream>>>(xacc, steps, sumh, out0, out1, out2, N);
  }
}

// Round 5
// 583.901 us; speedup vs baseline: 3.2932x; 3.2932x over previous
//
#include <hip/hip_runtime.h>
#include <hip/hip_bf16.h>

#define F_IN 512
#define NC 64      // HID == N_CLS == 64
#define NITER 10
#define BM 64      // MLP tile rows
#define BK 64      // MLP K tile

// ---------------------------------------------------------------------------
// Init per-node halting state; also set rowptr[N] = E.
__global__ __launch_bounds__(256) void init_state_kernel(
    float* __restrict__ steps, float* __restrict__ sumh, int* __restrict__ cont,
    int* __restrict__ rowptr, int N, int E) {
  int i = blockIdx.x * blockDim.x + threadIdx.x;
  if (i < N) { steps[i] = 1.0f; sumh[i] = 0.0f; cont[i] = 1; }
  if (i == 0) rowptr[N] = E;
}

// ---------------------------------------------------------------------------
// Fused tiled MLP: out[r,:] = relu(x[r,:] @ W1 + b1) @ W2 + b2   (all fp32)
// Block: 64 rows x 64 cols, 256 threads, 4x4 outputs per thread.
// xT layout: element (k, r) at xT[k*64 + (r ^ (k & 28))]  (2-way max on LDS).
__global__ __launch_bounds__(256) void mlp_kernel(
    const float* __restrict__ x, const float* __restrict__ W1,
    const float* __restrict__ b1, const float* __restrict__ W2,
    const float* __restrict__ b2, float* __restrict__ out, int N) {
  __shared__ float xT[BK * BM];    // swizzled [k][row] x tile / later hT
  __shared__ float ws[BK * NC];    // W1 k-tile / later W2
  const int tid  = threadIdx.x;
  const int brow = blockIdx.x * BM;
  const int r0 = (tid >> 4) * 4;   // 16 row-groups of 4
  const int c0 = (tid & 15) * 4;   // 16 col-groups of 4

  float acc[4][4];
#pragma unroll
  for (int j = 0; j < 4; ++j) {
    float bv = b1[c0 + j];
#pragma unroll
    for (int i = 0; i < 4; ++i) acc[i][j] = bv;
  }

  for (int kt = 0; kt < F_IN; kt += BK) {
    // stage x tile (64 rows x 64 k), transposed+swizzled into xT
#pragma unroll
    for (int q = 0; q < 4; ++q) {
      int fidx = q * 256 + tid;          // over 1024 float4s
      int row = fidx >> 4, kq = fidx & 15;
      int gr = brow + row; if (gr >= N) gr = N - 1;
      float4 v = *reinterpret_cast<const float4*>(&x[(size_t)gr * F_IN + kt + kq * 4]);
      float vv[4] = {v.x, v.y, v.z, v.w};
#pragma unroll
      for (int j = 0; j < 4; ++j) {
        int kk = kq * 4 + j;
        xT[kk * BM + (row ^ (kk & 28))] = vv[j];
      }
    }
    // stage W1 k-tile (64 x 64), row-major
#pragma unroll
    for (int q = 0; q < 4; ++q) {
      int fidx = q * 256 + tid;          // over 1024 float4s
      int row = fidx >> 4, kq = fidx & 15;
      *reinterpret_cast<float4*>(&ws[row * NC + kq * 4]) =
          *reinterpret_cast<const float4*>(&W1[(size_t)(kt + row) * NC + kq * 4]);
    }
    __syncthreads();
#pragma unroll 8
    for (int k = 0; k < BK; ++k) {
      float4 xa = *reinterpret_cast<const float4*>(&xT[k * BM + (r0 ^ (k & 28))]);
      float4 wv = *reinterpret_cast<const float4*>(&ws[k * NC + c0]);
      float xr[4] = {xa.x, xa.y, xa.z, xa.w};
      float wr[4] = {wv.x, wv.y, wv.z, wv.w};
#pragma unroll
      for (int i = 0; i < 4; ++i)
#pragma unroll
        for (int j = 0; j < 4; ++j) acc[i][j] = fmaf(xr[i], wr[j], acc[i][j]);
    }
    __syncthreads();
  }

  // ReLU; write h transposed+swizzled into xT space; stage W2 into ws
#pragma unroll
  for (int i = 0; i < 4; ++i)
#pragma unroll
    for (int j = 0; j < 4; ++j) {
      int kk = c0 + j;
      int r  = r0 + i;
      xT[kk * BM + (r ^ (kk & 28))] = fmaxf(acc[i][j], 0.0f);
    }
#pragma unroll
  for (int q = 0; q < 4; ++q) {
    int fidx = q * 256 + tid;
    int row = fidx >> 4, kq = fidx & 15;
    *reinterpret_cast<float4*>(&ws[row * NC + kq * 4]) =
        *reinterpret_cast<const float4*>(&W2[(size_t)row * NC + kq * 4]);
  }
  float acc2[4][4];
#pragma unroll
  for (int j = 0; j < 4; ++j) {
    float bv = b2[c0 + j];
#pragma unroll
    for (int i = 0; i < 4; ++i) acc2[i][j] = bv;
  }
  __syncthreads();
#pragma unroll 8
  for (int k = 0; k < NC; ++k) {
    float4 xa = *reinterpret_cast<const float4*>(&xT[k * BM + (r0 ^ (k & 28))]);
    float4 wv = *reinterpret_cast<const float4*>(&ws[k * NC + c0]);
    float xr[4] = {xa.x, xa.y, xa.z, xa.w};
    float wr[4] = {wv.x, wv.y, wv.z, wv.w};
#pragma unroll
    for (int i = 0; i < 4; ++i)
#pragma unroll
      for (int j = 0; j < 4; ++j) acc2[i][j] = fmaf(xr[i], wr[j], acc2[i][j]);
  }
#pragma unroll
  for (int i = 0; i < 4; ++i) {
    int gr = brow + r0 + i;
    if (gr < N) {
      float4 o = make_float4(acc2[i][0], acc2[i][1], acc2[i][2], acc2[i][3]);
      *reinterpret_cast<float4*>(&out[(size_t)gr * NC + c0]) = o;
    }
  }
}

// ---------------------------------------------------------------------------
// Degree histograms: deg_i counts sources (for GCN norm), indeg counts
// destinations (for the pull-CSR). Int atomics -> deterministic.
__global__ __launch_bounds__(256) void hist_kernel(
    const int* __restrict__ ei, int* __restrict__ deg_i,
    int* __restrict__ indeg, int E) {
  int e = blockIdx.x * blockDim.x + threadIdx.x;
  if (e < E) {
    atomicAdd(&deg_i[ei[e]], 1);       // row = edge_index[0]
    atomicAdd(&indeg[ei[E + e]], 1);   // col = edge_index[1]
  }
}

// dis[i] = 1/sqrt(deg_i[i] + 1)   (+1 = self loop; deg always >= 1)
__global__ __launch_bounds__(256) void dis_kernel(
    const int* __restrict__ deg_i, float* __restrict__ dis, int N) {
  int i = blockIdx.x * blockDim.x + threadIdx.x;
  if (i < N) dis[i] = 1.0f / sqrtf((float)(deg_i[i] + 1));
}

// ---------------------------------------------------------------------------
// 3-kernel exclusive scan of indeg -> rowptr  (N = 50000, 196 blocks of 256)
__global__ __launch_bounds__(256) void scan_sum_kernel(
    const int* __restrict__ indeg, int* __restrict__ bsum, int N) {
  __shared__ int sm[256];
  int tid = threadIdx.x;
  int i = blockIdx.x * 256 + tid;
  sm[tid] = (i < N) ? indeg[i] : 0;
  __syncthreads();
  for (int s = 128; s > 0; s >>= 1) {
    if (tid < s) sm[tid] += sm[tid + s];
    __syncthreads();
  }
  if (tid == 0) bsum[blockIdx.x] = sm[0];
}

__global__ __launch_bounds__(256) void scan_bsum_kernel(int* __restrict__ bsum, int nb) {
  __shared__ int sm[256];
  int tid = threadIdx.x;
  int v = (tid < nb) ? bsum[tid] : 0;
  sm[tid] = v;
  __syncthreads();
  for (int s = 1; s < 256; s <<= 1) {
    int t = (tid >= s) ? sm[tid - s] : 0;
    __syncthreads();
    sm[tid] += t;
    __syncthreads();
  }
  if (tid < nb) bsum[tid] = sm[tid] - v;  // exclusive
}

__global__ __launch_bounds__(256) void scan_final_kernel(
    const int* __restrict__ indeg, const int* __restrict__ bsum,
    int* __restrict__ rowptr, int N) {
  __shared__ int sm[256];
  int tid = threadIdx.x;
  int i = blockIdx.x * 256 + tid;
  int v = (i < N) ? indeg[i] : 0;
  sm[tid] = v;
  __syncthreads();
  for (int s = 1; s < 256; s <<= 1) {
    int t = (tid >= s) ? sm[tid - s] : 0;
    __syncthreads();
    sm[tid] += t;
    __syncthreads();
  }
  if (i < N) rowptr[i] = bsum[blockIdx.x] + sm[tid] - v;
}

// ---------------------------------------------------------------------------
// Build destination-CSR entries: csr[pos] = {src, norm} packed as int2.
__global__ __launch_bounds__(256) void scatter_kernel(
    const int* __restrict__ ei, const int* __restrict__ rowptr,
    int* __restrict__ cursor, const float* __restrict__ dis,
    int2* __restrict__ csr, int E) {
  int e = blockIdx.x * blockDim.x + threadIdx.x;
  if (e < E) {
    int s = ei[e];
    int c = ei[E + e];
    int pos = rowptr[c] + atomicAdd(&cursor[c], 1);
    csr[pos] = make_int2(s, __float_as_int(dis[s] * dis[c]));
  }
}

// ---------------------------------------------------------------------------
// One adaptive-propagation step, fully fused. One 64-lane wave per node,
// lane = feature. Pull-based gather over incoming edges, no atomics.
// 8 accumulators -> 8 outstanding gathers to cover L2/L3 latency.
__global__ __launch_bounds__(256) void prop_step_kernel(
    const float* __restrict__ prop, float* __restrict__ prop_new,
    const int2* __restrict__ csr, const int* __restrict__ rowptr,
    const float* __restrict__ dis, const float* __restrict__ hw,
    const float* __restrict__ hb, float* __restrict__ steps,
    float* __restrict__ sumh, int* __restrict__ cont,
    float* __restrict__ xacc, int N) {
  int wid = (int)((blockIdx.x * blockDim.x + threadIdx.x) >> 6);
  if (wid >= N) return;
  int lane = threadIdx.x & 63;
  size_t rowoff = (size_t)wid * NC + lane;

  float oldv = prop[rowoff];
  float dc = dis[wid];
  int beg = __builtin_amdgcn_readfirstlane(rowptr[wid]);
  int end = __builtin_amdgcn_readfirstlane(rowptr[wid + 1]);

  // self-loop: norm = dis[c]^2
  float a[8];
  a[0] = dc * dc * oldv;
#pragma unroll
  for (int u = 1; u < 8; ++u) a[u] = 0.0f;
  int i = beg;
  for (; i + 8 <= end; i += 8) {   // 8 outstanding gathers
    int2 e[8];
#pragma unroll
    for (int u = 0; u < 8; ++u) e[u] = csr[i + u];
#pragma unroll
    for (int u = 0; u < 8; ++u)
      a[u] = fmaf(__int_as_float(e[u].y), prop[(size_t)e[u].x * NC + lane], a[u]);
  }
  for (; i < end; ++i) {
    int2 e0 = csr[i];
    a[0] = fmaf(__int_as_float(e0.y), prop[(size_t)e0.x * NC + lane], a[0]);
  }
  float acc = ((a[0] + a[1]) + (a[2] + a[3])) + ((a[4] + a[5]) + (a[6] + a[7]));
  prop_new[rowoff] = acc;

  // hh = sigmoid(prop_new[c,:] . halt_w + halt_b)
  float z = acc * hw[lane];
#pragma unroll
  for (int off = 32; off > 0; off >>= 1) z += __shfl_xor(z, off);
  z += hb[0];
  float hh = 1.0f / (1.0f + expf(-z));

  float st = steps[wid], sh = sumh[wid];
  int ct = cont[wid];
  bool prob = ((sh + hh) < 0.99f) && (ct != 0);
  float pf = prob ? 1.0f : 0.0f;
  st += pf;
  sh += pf * hh;
  bool cond = prob && (st < (float)NITER);
  float pp = cond ? sh : (1.0f - sh);
  float ctf = ct ? 1.0f : 0.0f;
  xacc[rowoff] += (acc * pp + oldv * (1.0f - pp)) * ctf;
  if (lane == 0) { steps[wid] = st; sumh[wid] = sh; cont[wid] = prob ? 1 : 0; }
}

// ---------------------------------------------------------------------------
// out0 = log_softmax(xacc/steps), out1 = steps, out2 = 1 - sum_h
__global__ __launch_bounds__(256) void final_kernel(
    const float* __restrict__ xacc, const float* __restrict__ steps,
    const float* __restrict__ sumh, float* __restrict__ out0,
    float* __restrict__ out1, float* __restrict__ out2, int N) {
  int wid = (int)((blockIdx.x * blockDim.x + threadIdx.x) >> 6);
  if (wid >= N) return;
  int lane = threadIdx.x & 63;
  float st = steps[wid];
  float v = xacc[(size_t)wid * NC + lane] / st;
  float m = v;
#pragma unroll
  for (int off = 32; off > 0; off >>= 1) m = fmaxf(m, __shfl_xor(m, off));
  float e = expf(v - m);
  float s = e;
#pragma unroll
  for (int off = 32; off > 0; off >>= 1) s += __shfl_xor(s, off);
  out0[(size_t)wid * NC + lane] = v - m - logf(s);
  if (lane == 0) { out1[wid] = st; out2[wid] = 1.0f - sumh[wid]; }
}

// ---------------------------------------------------------------------------
extern "C" void kernel_launch(void* const* d_in, const int* in_sizes, int n_in,
                              void* d_out, int out_size, void* d_ws, size_t ws_size,
                              hipStream_t stream) {
  const float* x      = (const float*)d_in[0];
  const int*   ei     = (const int*)d_in[1];
  const float* W1     = (const float*)d_in[2];
  const float* b1     = (const float*)d_in[3];
  const float* W2     = (const float*)d_in[4];
  const float* b2     = (const float*)d_in[5];
  const float* halt_w = (const float*)d_in[6];
  const float* halt_b = (const float*)d_in[7];

  const int N = in_sizes[0] / F_IN;   // 50000
  const int E = in_sizes[1] / 2;      // 800000

  // workspace carve-up (256B aligned)
  char* p = (char*)d_ws;
  auto alloc = [&](size_t bytes) {
    void* r = (void*)p;
    p += (bytes + 255) & ~(size_t)255;
    return r;
  };
  float* propA  = (float*)alloc((size_t)N * NC * 4);
  float* propB  = (float*)alloc((size_t)N * NC * 4);
  float* xacc   = (float*)alloc((size_t)N * NC * 4);
  int2*  csr    = (int2*)alloc((size_t)E * 8);
  int*   rowptr = (int*)alloc((size_t)(N + 1) * 4);
  int*   deg_i  = (int*)alloc((size_t)N * 4);
  int*   indeg  = (int*)alloc((size_t)N * 4);
  int*   cursor = (int*)alloc((size_t)N * 4);
  float* dis    = (float*)alloc((size_t)N * 4);
  float* steps  = (float*)alloc((size_t)N * 4);
  float* sumh   = (float*)alloc((size_t)N * 4);
  int*   cont   = (int*)alloc((size_t)N * 4);
  int*   bsum   = (int*)alloc(1024);

  hipMemsetAsync(deg_i,  0, (size_t)N * 4, stream);
  hipMemsetAsync(indeg,  0, (size_t)N * 4, stream);
  hipMemsetAsync(cursor, 0, (size_t)N * 4, stream);
  hipMemsetAsync(xacc,   0, (size_t)N * NC * 4, stream);

  const int nbN = (N + 255) / 256;   // 196
  const int nbE = (E + 255) / 256;   // 3125
  const int nbM = (N + BM - 1) / BM; // 782

  init_state_kernel<<<nbN, 256, 0, stream>>>(steps, sumh, cont, rowptr, N, E);
  mlp_kernel<<<nbM, 256, 0, stream>>>(x, W1, b1, W2, b2, propA, N);
  hist_kernel<<<nbE, 256, 0, stream>>>(ei, deg_i, indeg, E);
  dis_kernel<<<nbN, 256, 0, stream>>>(deg_i, dis, N);
  scan_sum_kernel<<<nbN, 256, 0, stream>>>(indeg, bsum, N);
  scan_bsum_kernel<<<1, 256, 0, stream>>>(bsum, nbN);
  scan_final_kernel<<<nbN, 256, 0, stream>>>(indeg, bsum, rowptr, N);
  scatter_kernel<<<nbE, 256, 0, stream>>>(ei, rowptr, cursor, dis, csr, E);

  float* out0 = (float*)d_out;
  float* out1 = out0 + (size_t)N * NC;
  float* out2 = out1 + N;

  const float* cur = propA;
  float* nxt = propB;
  const int nbW = (N + 3) / 4;       // 4 waves (nodes) per 256-thread block
  for (int it = 0; it < NITER; ++it) {
    prop_step_kernel<<<nbW, 256, 0, stream>>>(cur, nxt, csr, rowptr, dis,
                                              halt_w, halt_b, steps, sumh,
                                              cont, xacc, N);
    const float* t = nxt; nxt = (float*)cur; cur = t;
  }
  final_kernel<<<nbW, 256, 0, stream>>>(xacc, steps, sumh, out0, out1, out2, N);
}